// Round 10
// baseline (257.998 us; speedup 1.0000x reference)
//
#include <hip/hip_runtime.h>
#include <hip/hip_bf16.h>

#define NEG_SLOPE 0.2f
#define LN_EPS 1e-5f
#define SM_EPS 1e-16f

typedef __attribute__((ext_vector_type(8))) short bf16x8;
typedef __attribute__((ext_vector_type(4))) float f32x4;

__device__ inline unsigned short f2bf(float f) {
    unsigned u = __float_as_uint(f);
    return (unsigned short)((u + 0x7FFFu + ((u >> 16) & 1u)) >> 16);
}
__device__ inline float bf_lo(unsigned int v) { return __uint_as_float(v << 16); }
__device__ inline float bf_hi(unsigned int v) { return __uint_as_float(v & 0xffff0000u); }

#define NBIN 512           // bins = dst>>8 (256 dsts per bin); ~391 occupied at N=100k
#define BCAP 4864          // slots per bin: mean E/391 ~= 4092, sigma ~64 -> +12 sigma
#define SCHUNK 4096        // edges per scatter block (16/thread)
#define CURPAD 16          // binCursor stride in ints -> one counter per 64B line

// ---------------------------------------------------------------------------
// k_gs: heterogeneous fused dispatch. Blocks [0,SB) run the scatter body
// (reads ei only), blocks [SB,SB+GB) run the GEMM body (reads X,W only).
// GEMM epilogue stores factorized attention weights:
//   PS[n] = {e^aS0, e^(0.2 aS0), e^aS1, e^(0.2 aS1)}, PD[n] likewise, so
// downstream weight eval is exp-free: exp(leaky(aS+aD)) == (eS*eD >= 1)
// ? eS*eD : eSp*eDp. binCursor bin-RELATIVE, init by hipMemsetAsync.
// ---------------------------------------------------------------------------
__global__ __launch_bounds__(256) void k_gs(const float* __restrict__ X,
                                            const float* __restrict__ W,
                                            const float* __restrict__ att_src,
                                            const float* __restrict__ att_dst,
                                            unsigned int* __restrict__ xp,
                                            float4* __restrict__ PS,
                                            float4* __restrict__ PD,
                                            const int* __restrict__ ei,
                                            int* __restrict__ binCursor,
                                            unsigned int* __restrict__ tmp,
                                            int N, int E, int SB) {
    __shared__ __align__(16) char smem[52224];
    const int t = threadIdx.x;

    if ((int)blockIdx.x < SB) {
        // ---------------- scatter body: pure streaming binner ----------------
        int* off = (int*)smem;
        const int base = blockIdx.x * SCHUNK;

        int bn[16];
        unsigned int pe[16];
#pragma unroll
        for (int k = 0; k < 16; ++k) {
            int i = base + k * 256 + t;
            if (i < E) {
                int s = ei[i];
                int d = ei[E + i];
                bn[k] = d >> 8;
                pe[k] = ((unsigned)(d & 255) << 24) | (unsigned)s;
            } else {
                bn[k] = -1;
            }
        }

        for (int i = t; i < NBIN; i += 256) off[i] = 0;
        __syncthreads();
#pragma unroll
        for (int k = 0; k < 16; ++k)
            if (bn[k] >= 0) atomicAdd(&off[bn[k]], 1);
        __syncthreads();
        for (int i = t; i < NBIN; i += 256) {
            int h = off[i];
            off[i] = h ? (atomicAdd(&binCursor[i * CURPAD], h) + i * BCAP) : 0;
        }
        __syncthreads();
#pragma unroll
        for (int k = 0; k < 16; ++k) {
            if (bn[k] >= 0) {
                int p = atomicAdd(&off[bn[k]], 1);
                tmp[p] = pe[k];
            }
        }
        return;
    }

    // ---------------- GEMM body: bf16 MFMA + attention dots ----------------
    unsigned short* Ws = (unsigned short*)smem;                 // 128*136 ushort
    unsigned short* Xs = (unsigned short*)(smem + 34816);       //  64*136 ushort
    const int b0 = ((int)blockIdx.x - SB) * 64;
    const int lane = t & 63;
    const int w = t >> 6;
    const int c15 = lane & 15;
    const int quad = lane >> 4;

#pragma unroll
    for (int i = 0; i < 16; ++i) {
        int f = i * 256 + t;
        int nr = f >> 5;
        int q = f & 31;
        float4 v = reinterpret_cast<const float4*>(W)[nr * 32 + q];
        ushort4 b;
        b.x = f2bf(v.x); b.y = f2bf(v.y); b.z = f2bf(v.z); b.w = f2bf(v.w);
        *reinterpret_cast<ushort4*>(&Ws[nr * 136 + q * 4]) = b;
    }
#pragma unroll
    for (int i = 0; i < 8; ++i) {
        int f = i * 256 + t;
        int m = f >> 5;
        int q = f & 31;
        int gr = b0 + m;
        if (gr >= N) gr = N - 1;
        float4 v = reinterpret_cast<const float4*>(X)[(size_t)gr * 32 + q];
        ushort4 b;
        b.x = f2bf(v.x); b.y = f2bf(v.y); b.z = f2bf(v.z); b.w = f2bf(v.w);
        *reinterpret_cast<ushort4*>(&Xs[m * 136 + q * 4]) = b;
    }
    __syncthreads();

    f32x4 acc[8];
#pragma unroll
    for (int ct = 0; ct < 8; ++ct) acc[ct] = (f32x4){0.f, 0.f, 0.f, 0.f};

#pragma unroll
    for (int kc = 0; kc < 4; ++kc) {
        bf16x8 af = *reinterpret_cast<const bf16x8*>(
            &Xs[(w * 16 + c15) * 136 + kc * 32 + quad * 8]);
#pragma unroll
        for (int ct = 0; ct < 8; ++ct) {
            bf16x8 bfr = *reinterpret_cast<const bf16x8*>(
                &Ws[(ct * 16 + c15) * 136 + kc * 32 + quad * 8]);
            acc[ct] = __builtin_amdgcn_mfma_f32_16x16x32_bf16(af, bfr, acc[ct], 0, 0, 0);
        }
    }

    float attS[8], attD[8];
#pragma unroll
    for (int ct = 0; ct < 8; ++ct) {
        attS[ct] = att_src[ct * 16 + c15];
        attD[ct] = att_dst[ct * 16 + c15];
    }

#pragma unroll
    for (int r = 0; r < 4; ++r) {
        int row = b0 + w * 16 + quad * 4 + r;
        float s0 = 0.f, s1 = 0.f, d0 = 0.f, d1 = 0.f;
#pragma unroll
        for (int ct = 0; ct < 4; ++ct) {
            s0 += acc[ct][r] * attS[ct];
            d0 += acc[ct][r] * attD[ct];
            s1 += acc[ct + 4][r] * attS[ct + 4];
            d1 += acc[ct + 4][r] * attD[ct + 4];
        }
#pragma unroll
        for (int o = 1; o < 16; o <<= 1) {
            s0 += __shfl_xor(s0, o);
            s1 += __shfl_xor(s1, o);
            d0 += __shfl_xor(d0, o);
            d1 += __shfl_xor(d1, o);
        }
        if (row < N) {
#pragma unroll
            for (int ct = 0; ct < 4; ++ct) {
                unsigned int p = (unsigned int)f2bf(acc[ct][r]) |
                                 ((unsigned int)f2bf(acc[ct + 4][r]) << 16);
                xp[(size_t)row * 64 + ct * 16 + c15] = p;
            }
            if (c15 == 0) {
                PS[row] = make_float4(__expf(s0), __expf(NEG_SLOPE * s0),
                                      __expf(s1), __expf(NEG_SLOPE * s1));
                PD[row] = make_float4(__expf(d0), __expf(NEG_SLOPE * d0),
                                      __expf(d1), __expf(NEG_SLOPE * d1));
            }
        }
    }
}

// ---------------------------------------------------------------------------
// k_bucket: one block per 256-dst bin, 512 threads, TWO passes (the proven
// round-7 shape; round-9's 1024-thread single-pass + den atomics + metaN
// cost ~24us). P1: cnt histogram only (1 LDS atomic/edge). Scan -> packed
// rowPtr {beg|cnt<<22}. P2: re-read tmp (L2-hot), gather PS[src] (L2-hot
// 1.6MB), factorized exp-free weight u01, counting-sort write of csr uint2
// {src,u01}. Denominators are NOT computed here — k_agg accumulates them
// in-loop from the same bf16 weights (round-2 precedent: ~+1us there).
// ---------------------------------------------------------------------------
__global__ __launch_bounds__(512) void k_bucket(const unsigned int* __restrict__ tmp,
                                                const int* __restrict__ binCursor,
                                                const float4* __restrict__ PS,
                                                const float4* __restrict__ PD,
                                                uint2* __restrict__ csr,
                                                unsigned int* __restrict__ rowPtr,
                                                int N) {
    __shared__ int cnt[256];
    __shared__ int cur[256];
    __shared__ int lds[4];
    __shared__ float4 pdc[256];
    const int t = threadIdx.x;
    const int b = blockIdx.x;
    const int start = b * BCAP;
    const int d0 = b * 256;
    int m = binCursor[b * CURPAD];
    if (m > BCAP) m = BCAP;   // statistically unreachable guard

    if (t < 256) {
        cnt[t] = 0;
        int d = d0 + t;
        pdc[t] = (d < N) ? PD[d] : make_float4(0.f, 0.f, 0.f, 0.f);
    }
    __syncthreads();

    for (int k = t; k < m; k += 512) {
        atomicAdd(&cnt[tmp[start + k] >> 24], 1);
    }
    __syncthreads();

    const int lane = t & 63, w = t >> 6;
    int v = 0, incl = 0;
    if (t < 256) {                 // waves 0-3 fully active -> shfl safe
        v = cnt[t];
        incl = v;
#pragma unroll
        for (int o = 1; o < 64; o <<= 1) {
            int u = __shfl_up(incl, o);
            if (lane >= o) incl += u;
        }
        if (lane == 63) lds[w] = incl;
    }
    __syncthreads();
    if (t == 0) {
        int run = 0;
        for (int i = 0; i < 4; ++i) { int tv = lds[i]; lds[i] = run; run += tv; }
    }
    __syncthreads();
    if (t < 256) {
        int excl = lds[w] + incl - v;
        cur[t] = excl;
        int d = d0 + t;
        if (d < N) rowPtr[d] = (unsigned)(start + excl) | ((unsigned)v << 22);
    }
    __syncthreads();

    // P2: weight + counting-sort placement
    for (int k = t; k < m; k += 512) {
        unsigned int e = tmp[start + k];
        int li = e >> 24;
        int s = (int)(e & 0x00FFFFFFu);
        float4 ps = PS[s];
        float4 pd = pdc[li];
        float m0 = ps.x * pd.x, mp0 = ps.y * pd.y;
        float m1 = ps.z * pd.z, mp1 = ps.w * pd.w;
        float u0 = (m0 >= 1.f) ? m0 : mp0;
        float u1 = (m1 >= 1.f) ? m1 : mp1;
        unsigned int u01;
        asm("v_cvt_pk_bf16_f32 %0, %1, %2" : "=v"(u01) : "v"(u0), "v"(u1));
        int p = atomicAdd(&cur[li], 1);
        csr[start + p] = make_uint2((unsigned)s, u01);
    }
}

// ---------------------------------------------------------------------------
// K5: per-dst aggregation + bias + LayerNorm. Champion SGPR-weight structure
// (round 9: 64us @ 42% VALU / 12 VGPR), upgraded to TWO dsts per wave in
// lockstep: 16 independent xp gathers in flight (was 8; kernel is
// latency-bound, nothing saturated) and serial batch count = ceil(max(dA,
// dB)/8) instead of ceil(dA/8)+ceil(dB/8). Degree mismatch handled by
// clamp-to-last index + zero-weight (uniform SALU select) -> no tail loops.
// Denominators accumulated in-loop from the same bf16 weights; self weight
// from uniform PS[n]/PD[n] loads (exp-free factorization).
// ---------------------------------------------------------------------------
__global__ __launch_bounds__(256) void k_agg(const unsigned int* __restrict__ xp,
                                             const float4* __restrict__ PS,
                                             const float4* __restrict__ PD,
                                             const unsigned int* __restrict__ rowPtr,
                                             const uint2* __restrict__ csr,
                                             const float* __restrict__ bias,
                                             const float* __restrict__ gamma,
                                             const float* __restrict__ beta,
                                             float* __restrict__ out, int N) {
    const int w = threadIdx.x >> 6, lane = threadIdx.x & 63;
    const int pidx = blockIdx.x * 4 + w;
    const int n0 = pidx * 2;
    if (n0 >= N) return;
    const bool hasB = (n0 + 1 < N);
    const int n1 = hasB ? n0 + 1 : n0;

    // self weights from factorized exps (f32, unquantized)
    float4 psA = PS[n0], pdA = PD[n0];
    float4 psB = PS[n1], pdB = PD[n1];
    float mA0 = psA.x * pdA.x, mpA0 = psA.y * pdA.y;
    float mA1 = psA.z * pdA.z, mpA1 = psA.w * pdA.w;
    float usA0 = (mA0 >= 1.f) ? mA0 : mpA0;
    float usA1 = (mA1 >= 1.f) ? mA1 : mpA1;
    float mB0 = psB.x * pdB.x, mpB0 = psB.y * pdB.y;
    float mB1 = psB.z * pdB.z, mpB1 = psB.w * pdB.w;
    float usB0 = (mB0 >= 1.f) ? mB0 : mpB0;
    float usB1 = (mB1 >= 1.f) ? mB1 : mpB1;

    unsigned int vsA = xp[((unsigned)n0 << 6) | lane];
    unsigned int vsB = xp[((unsigned)n1 << 6) | lane];
    float SA0 = usA0 * bf_lo(vsA), SA1 = usA1 * bf_hi(vsA);
    float SB0 = usB0 * bf_lo(vsB), SB1 = usB1 * bf_hi(vsB);
    float DA0 = usA0, DA1 = usA1, DB0 = usB0, DB1 = usB1;

    unsigned int prA = rowPtr[n0];
    unsigned int prB = rowPtr[n1];
    int jA = (int)(prA & 0x3FFFFFu), degA = (int)(prA >> 22);
    int jB = (int)(prB & 0x3FFFFFu), degB = hasB ? (int)(prB >> 22) : 0;
    const int lastA = jA + (degA > 0 ? degA - 1 : 0);
    const int lastB = jB + (degB > 0 ? degB - 1 : 0);
    int remA = degA, remB = degB;
    const int dmax = (degA > degB) ? degA : degB;
    const int nb = (dmax + 7) >> 3;

    uint2 ca[8], cb[8];
    if (nb > 0) {
        int juA = __builtin_amdgcn_readfirstlane(jA);
        int juB = __builtin_amdgcn_readfirstlane(jB);
#pragma unroll
        for (int q = 0; q < 8; ++q) {
            int ia = juA + q; if (ia > lastA) ia = lastA;
            int ib = juB + q; if (ib > lastB) ib = lastB;
            ca[q] = csr[ia];
            cb[q] = csr[ib];
        }
    }

    for (int bI = 0; bI < nb; ++bI) {
        unsigned int va[8], vb[8];
#pragma unroll
        for (int q = 0; q < 8; ++q) {
            va[q] = xp[(ca[q].x << 6) | lane];
            vb[q] = xp[(cb[q].x << 6) | lane];
        }
        // prefetch next batch's csr entries (re-read base on last iteration)
        uint2 na2[8], nb2[8];
        {
            int stp = (bI + 1 < nb) ? 8 : 0;
            int juA = __builtin_amdgcn_readfirstlane(jA + stp);
            int juB = __builtin_amdgcn_readfirstlane(jB + stp);
#pragma unroll
            for (int q = 0; q < 8; ++q) {
                int ia = juA + q; if (ia > lastA) ia = lastA;
                int ib = juB + q; if (ib > lastB) ib = lastB;
                na2[q] = csr[ia];
                nb2[q] = csr[ib];
            }
        }
#pragma unroll
        for (int q = 0; q < 8; ++q) {
            unsigned int uya = (q < remA) ? ca[q].y : 0u;   // uniform select
            unsigned int uyb = (q < remB) ? cb[q].y : 0u;
            float wa0 = bf_lo(uya), wa1 = bf_hi(uya);
            float wb0 = bf_lo(uyb), wb1 = bf_hi(uyb);
            DA0 += wa0; DA1 += wa1;
            DB0 += wb0; DB1 += wb1;
            SA0 = fmaf(wa0, bf_lo(va[q]), SA0);
            SA1 = fmaf(wa1, bf_hi(va[q]), SA1);
            SB0 = fmaf(wb0, bf_lo(vb[q]), SB0);
            SB1 = fmaf(wb1, bf_hi(vb[q]), SB1);
        }
#pragma unroll
        for (int q = 0; q < 8; ++q) { ca[q] = na2[q]; cb[q] = nb2[q]; }
        jA += 8; jB += 8; remA -= 8; remB -= 8;
    }

    float gm = gamma[lane], bt = beta[lane], bs = bias[lane];

    float oA = (0.5f / (DA0 + SM_EPS)) * SA0 + (0.5f / (DA1 + SM_EPS)) * SA1 + bs;
    float mu = oA;
#pragma unroll
    for (int d = 32; d > 0; d >>= 1) mu += __shfl_xor(mu, d);
    mu *= (1.0f / 64.0f);
    float dv = oA - mu;
    float var = dv * dv;
#pragma unroll
    for (int d = 32; d > 0; d >>= 1) var += __shfl_xor(var, d);
    var *= (1.0f / 64.0f);
    out[(size_t)n0 * 64 + lane] = dv * rsqrtf(var + LN_EPS) * gm + bt;

    if (hasB) {
        float oB = (0.5f / (DB0 + SM_EPS)) * SB0 + (0.5f / (DB1 + SM_EPS)) * SB1 + bs;
        float mu2 = oB;
#pragma unroll
        for (int d = 32; d > 0; d >>= 1) mu2 += __shfl_xor(mu2, d);
        mu2 *= (1.0f / 64.0f);
        float dv2 = oB - mu2;
        float var2 = dv2 * dv2;
#pragma unroll
        for (int d = 32; d > 0; d >>= 1) var2 += __shfl_xor(var2, d);
        var2 *= (1.0f / 64.0f);
        out[(size_t)n1 * 64 + lane] = dv2 * rsqrtf(var2 + LN_EPS) * gm + bt;
    }
}

// ---------------------------------------------------------------------------
extern "C" void kernel_launch(void* const* d_in, const int* in_sizes, int n_in,
                              void* d_out, int out_size, void* d_ws, size_t ws_size,
                              hipStream_t stream) {
    const float* X        = (const float*)d_in[0];
    const int*   ei       = (const int*)d_in[1];
    const float* W        = (const float*)d_in[2];
    const float* att_src  = (const float*)d_in[3];
    const float* att_dst  = (const float*)d_in[4];
    const float* bias     = (const float*)d_in[5];
    const float* ln_gamma = (const float*)d_in[6];
    const float* ln_beta  = (const float*)d_in[7];
    float* out = (float*)d_out;

    const int N = in_sizes[0] / 128;
    const int E = in_sizes[1] / 2;
    const int NBUCK = (N + 255) / 256;
    const int SB = (E + SCHUNK - 1) / SCHUNK;
    const int GB = (N + 63) / 64;
    const int NPAIR = (N + 1) / 2;

    char* ws = (char*)d_ws;
    size_t off = 0;
    auto alloc = [&](size_t bytes) {
        size_t o = off;
        off += (bytes + 255) & ~(size_t)255;
        return o;
    };
    unsigned int* xp     = (unsigned int*)(ws + alloc((size_t)N * 64 * 4));
    float4* PS           = (float4*)(ws + alloc((size_t)N * 16));
    float4* PD           = (float4*)(ws + alloc((size_t)N * 16));
    unsigned int* rowPtr = (unsigned int*)(ws + alloc((size_t)N * 4));
    uint2* csr           = (uint2*)(ws + alloc((size_t)NBIN * BCAP * 8));
    unsigned int* tmp    = (unsigned int*)(ws + alloc((size_t)NBIN * BCAP * 4));
    int* binCursor       = (int*)(ws + alloc(NBIN * CURPAD * 4));

    hipMemsetAsync(binCursor, 0, (size_t)NBIN * CURPAD * 4, stream);
    k_gs<<<SB + GB, 256, 0, stream>>>(X, W, att_src, att_dst, xp, PS, PD,
                                      ei, binCursor, tmp, N, E, SB);
    k_bucket<<<NBUCK, 512, 0, stream>>>(tmp, binCursor, PS, PD, csr, rowPtr, N);
    k_agg<<<(NPAIR + 3) / 4, 256, 0, stream>>>(xp, PS, PD, rowPtr, csr,
                                               bias, ln_gamma, ln_beta, out, N);
}

// Round 11
// 222.314 us; speedup vs baseline: 1.1605x; 1.1605x over previous
//
#include <hip/hip_runtime.h>
#include <hip/hip_bf16.h>

#define NEG_SLOPE 0.2f
#define LN_EPS 1e-5f
#define SM_EPS 1e-16f

typedef __attribute__((ext_vector_type(8))) short bf16x8;
typedef __attribute__((ext_vector_type(4))) float f32x4;

__device__ inline unsigned short f2bf(float f) {
    unsigned u = __float_as_uint(f);
    return (unsigned short)((u + 0x7FFFu + ((u >> 16) & 1u)) >> 16);
}
__device__ inline float bf_lo(unsigned int v) { return __uint_as_float(v << 16); }
__device__ inline float bf_hi(unsigned int v) { return __uint_as_float(v & 0xffff0000u); }

#define NBIN 512           // bins = dst>>8 (256 dsts per bin); ~391 occupied at N=100k
#define BCAP 4864          // slots per bin: mean E/391 ~= 4092, sigma ~64 -> +12 sigma
#define SCHUNK 4096        // edges per scatter block (16/thread)
#define CURPAD 16          // binCursor stride in ints -> one counter per 64B line

// ---------------------------------------------------------------------------
// k_gs: heterogeneous fused dispatch. Blocks [0,SB) run the scatter body
// (reads ei only), blocks [SB,SB+GB) run the GEMM body (reads X,W only).
// GEMM epilogue stores factorized attention weights:
//   PS[n] = {e^aS0, e^(0.2 aS0), e^aS1, e^(0.2 aS1)}, PD[n] likewise, so
// downstream weight eval is exp-free: exp(leaky(aS+aD)) == (eS*eD >= 1)
// ? eS*eD : eSp*eDp. binCursor bin-RELATIVE, init by hipMemsetAsync.
// ---------------------------------------------------------------------------
__global__ __launch_bounds__(256) void k_gs(const float* __restrict__ X,
                                            const float* __restrict__ W,
                                            const float* __restrict__ att_src,
                                            const float* __restrict__ att_dst,
                                            unsigned int* __restrict__ xp,
                                            float4* __restrict__ PS,
                                            float4* __restrict__ PD,
                                            const int* __restrict__ ei,
                                            int* __restrict__ binCursor,
                                            unsigned int* __restrict__ tmp,
                                            int N, int E, int SB) {
    __shared__ __align__(16) char smem[52224];
    const int t = threadIdx.x;

    if ((int)blockIdx.x < SB) {
        // ---------------- scatter body: pure streaming binner ----------------
        int* off = (int*)smem;
        const int base = blockIdx.x * SCHUNK;

        int bn[16];
        unsigned int pe[16];
#pragma unroll
        for (int k = 0; k < 16; ++k) {
            int i = base + k * 256 + t;
            if (i < E) {
                int s = ei[i];
                int d = ei[E + i];
                bn[k] = d >> 8;
                pe[k] = ((unsigned)(d & 255) << 24) | (unsigned)s;
            } else {
                bn[k] = -1;
            }
        }

        for (int i = t; i < NBIN; i += 256) off[i] = 0;
        __syncthreads();
#pragma unroll
        for (int k = 0; k < 16; ++k)
            if (bn[k] >= 0) atomicAdd(&off[bn[k]], 1);
        __syncthreads();
        for (int i = t; i < NBIN; i += 256) {
            int h = off[i];
            off[i] = h ? (atomicAdd(&binCursor[i * CURPAD], h) + i * BCAP) : 0;
        }
        __syncthreads();
#pragma unroll
        for (int k = 0; k < 16; ++k) {
            if (bn[k] >= 0) {
                int p = atomicAdd(&off[bn[k]], 1);
                tmp[p] = pe[k];
            }
        }
        return;
    }

    // ---------------- GEMM body: bf16 MFMA + attention dots ----------------
    unsigned short* Ws = (unsigned short*)smem;                 // 128*136 ushort
    unsigned short* Xs = (unsigned short*)(smem + 34816);       //  64*136 ushort
    const int b0 = ((int)blockIdx.x - SB) * 64;
    const int lane = t & 63;
    const int w = t >> 6;
    const int c15 = lane & 15;
    const int quad = lane >> 4;

#pragma unroll
    for (int i = 0; i < 16; ++i) {
        int f = i * 256 + t;
        int nr = f >> 5;
        int q = f & 31;
        float4 v = reinterpret_cast<const float4*>(W)[nr * 32 + q];
        ushort4 b;
        b.x = f2bf(v.x); b.y = f2bf(v.y); b.z = f2bf(v.z); b.w = f2bf(v.w);
        *reinterpret_cast<ushort4*>(&Ws[nr * 136 + q * 4]) = b;
    }
#pragma unroll
    for (int i = 0; i < 8; ++i) {
        int f = i * 256 + t;
        int m = f >> 5;
        int q = f & 31;
        int gr = b0 + m;
        if (gr >= N) gr = N - 1;
        float4 v = reinterpret_cast<const float4*>(X)[(size_t)gr * 32 + q];
        ushort4 b;
        b.x = f2bf(v.x); b.y = f2bf(v.y); b.z = f2bf(v.z); b.w = f2bf(v.w);
        *reinterpret_cast<ushort4*>(&Xs[m * 136 + q * 4]) = b;
    }
    __syncthreads();

    f32x4 acc[8];
#pragma unroll
    for (int ct = 0; ct < 8; ++ct) acc[ct] = (f32x4){0.f, 0.f, 0.f, 0.f};

#pragma unroll
    for (int kc = 0; kc < 4; ++kc) {
        bf16x8 af = *reinterpret_cast<const bf16x8*>(
            &Xs[(w * 16 + c15) * 136 + kc * 32 + quad * 8]);
#pragma unroll
        for (int ct = 0; ct < 8; ++ct) {
            bf16x8 bfr = *reinterpret_cast<const bf16x8*>(
                &Ws[(ct * 16 + c15) * 136 + kc * 32 + quad * 8]);
            acc[ct] = __builtin_amdgcn_mfma_f32_16x16x32_bf16(af, bfr, acc[ct], 0, 0, 0);
        }
    }

    float attS[8], attD[8];
#pragma unroll
    for (int ct = 0; ct < 8; ++ct) {
        attS[ct] = att_src[ct * 16 + c15];
        attD[ct] = att_dst[ct * 16 + c15];
    }

#pragma unroll
    for (int r = 0; r < 4; ++r) {
        int row = b0 + w * 16 + quad * 4 + r;
        float s0 = 0.f, s1 = 0.f, d0 = 0.f, d1 = 0.f;
#pragma unroll
        for (int ct = 0; ct < 4; ++ct) {
            s0 += acc[ct][r] * attS[ct];
            d0 += acc[ct][r] * attD[ct];
            s1 += acc[ct + 4][r] * attS[ct + 4];
            d1 += acc[ct + 4][r] * attD[ct + 4];
        }
#pragma unroll
        for (int o = 1; o < 16; o <<= 1) {
            s0 += __shfl_xor(s0, o);
            s1 += __shfl_xor(s1, o);
            d0 += __shfl_xor(d0, o);
            d1 += __shfl_xor(d1, o);
        }
        if (row < N) {
#pragma unroll
            for (int ct = 0; ct < 4; ++ct) {
                unsigned int p = (unsigned int)f2bf(acc[ct][r]) |
                                 ((unsigned int)f2bf(acc[ct + 4][r]) << 16);
                xp[(size_t)row * 64 + ct * 16 + c15] = p;
            }
            if (c15 == 0) {
                PS[row] = make_float4(__expf(s0), __expf(NEG_SLOPE * s0),
                                      __expf(s1), __expf(NEG_SLOPE * s1));
                PD[row] = make_float4(__expf(d0), __expf(NEG_SLOPE * d0),
                                      __expf(d1), __expf(NEG_SLOPE * d1));
            }
        }
    }
}

// ---------------------------------------------------------------------------
// k_bucket: one block per 256-dst bin, 512 threads, two passes (proven
// round-7 shape; stayed out of rocprof top-5 in round 10). P1: cnt
// histogram (1 LDS atomic/edge). Scan -> packed rowPtr {beg|cnt<<22}.
// P2: re-read tmp (L2-hot), gather PS[src] (L2-hot 1.6MB), factorized
// exp-free weight u01, counting-sort write of csr uint2 {src,u01}.
// Denominators accumulate in k_agg (round-2 precedent: ~+1us there).
// ---------------------------------------------------------------------------
__global__ __launch_bounds__(512) void k_bucket(const unsigned int* __restrict__ tmp,
                                                const int* __restrict__ binCursor,
                                                const float4* __restrict__ PS,
                                                const float4* __restrict__ PD,
                                                uint2* __restrict__ csr,
                                                unsigned int* __restrict__ rowPtr,
                                                int N) {
    __shared__ int cnt[256];
    __shared__ int cur[256];
    __shared__ int lds[4];
    __shared__ float4 pdc[256];
    const int t = threadIdx.x;
    const int b = blockIdx.x;
    const int start = b * BCAP;
    const int d0 = b * 256;
    int m = binCursor[b * CURPAD];
    if (m > BCAP) m = BCAP;   // statistically unreachable guard

    if (t < 256) {
        cnt[t] = 0;
        int d = d0 + t;
        pdc[t] = (d < N) ? PD[d] : make_float4(0.f, 0.f, 0.f, 0.f);
    }
    __syncthreads();

    for (int k = t; k < m; k += 512) {
        atomicAdd(&cnt[tmp[start + k] >> 24], 1);
    }
    __syncthreads();

    const int lane = t & 63, w = t >> 6;
    int v = 0, incl = 0;
    if (t < 256) {                 // waves 0-3 fully active -> shfl safe
        v = cnt[t];
        incl = v;
#pragma unroll
        for (int o = 1; o < 64; o <<= 1) {
            int u = __shfl_up(incl, o);
            if (lane >= o) incl += u;
        }
        if (lane == 63) lds[w] = incl;
    }
    __syncthreads();
    if (t == 0) {
        int run = 0;
        for (int i = 0; i < 4; ++i) { int tv = lds[i]; lds[i] = run; run += tv; }
    }
    __syncthreads();
    if (t < 256) {
        int excl = lds[w] + incl - v;
        cur[t] = excl;
        int d = d0 + t;
        if (d < N) rowPtr[d] = (unsigned)(start + excl) | ((unsigned)v << 22);
    }
    __syncthreads();

    // P2: weight + counting-sort placement
    for (int k = t; k < m; k += 512) {
        unsigned int e = tmp[start + k];
        int li = e >> 24;
        int s = (int)(e & 0x00FFFFFFu);
        float4 ps = PS[s];
        float4 pd = pdc[li];
        float m0 = ps.x * pd.x, mp0 = ps.y * pd.y;
        float m1 = ps.z * pd.z, mp1 = ps.w * pd.w;
        float u0 = (m0 >= 1.f) ? m0 : mp0;
        float u1 = (m1 >= 1.f) ? m1 : mp1;
        unsigned int u01;
        asm("v_cvt_pk_bf16_f32 %0, %1, %2" : "=v"(u01) : "v"(u0), "v"(u1));
        int p = atomicAdd(&cur[li], 1);
        csr[start + p] = make_uint2((unsigned)s, u01);
    }
}

// ---------------------------------------------------------------------------
// K5: per-dst aggregation + bias + LayerNorm — single-dst champion structure
// (round 9: 64us @ 42% VALU / 12 VGPR; round-10 lesson: 2-dst pairing
// doubles per-wave state and wasted clamp gathers -> 112us, never again).
// Weights arrive packed in csr uint2 via uniform (readfirstlane-addressed)
// loads -> SGPRs; unpack is SALU; inner loop = 2 FMA + 2 den-adds per edge.
// Self weight from uniform PS[n]/PD[n] (exp-free factorization). 32-bit xp
// addressing. Next csr batch prefetched while gathers + FMAs run.
// ---------------------------------------------------------------------------
__global__ __launch_bounds__(256) void k_agg(const unsigned int* __restrict__ xp,
                                             const float4* __restrict__ PS,
                                             const float4* __restrict__ PD,
                                             const unsigned int* __restrict__ rowPtr,
                                             const uint2* __restrict__ csr,
                                             const float* __restrict__ bias,
                                             const float* __restrict__ gamma,
                                             const float* __restrict__ beta,
                                             float* __restrict__ out, int N) {
    const int w = threadIdx.x >> 6, lane = threadIdx.x & 63;
    const int n = blockIdx.x * 4 + w;
    if (n >= N) return;

    // self weight from factorized exps (f32, unquantized)
    float4 ps = PS[n], pd = PD[n];
    float sm0 = ps.x * pd.x, smp0 = ps.y * pd.y;
    float sm1 = ps.z * pd.z, smp1 = ps.w * pd.w;
    float us0 = (sm0 >= 1.f) ? sm0 : smp0;
    float us1 = (sm1 >= 1.f) ? sm1 : smp1;

    unsigned int vself = xp[((unsigned)n << 6) | lane];
    float S0 = us0 * bf_lo(vself);
    float S1 = us1 * bf_hi(vself);
    float D0 = us0, D1 = us1;

    unsigned int pr = rowPtr[n];
    const int jb = (int)(pr & 0x3FFFFFu);
    const int je = jb + (int)(pr >> 22);
    int j = jb;
    const int nfull = (je - jb) >> 3;

    uint2 cc[8];
    if (nfull > 0) {
        int ju = __builtin_amdgcn_readfirstlane(j);
#pragma unroll
        for (int q = 0; q < 8; ++q) cc[q] = csr[ju + q];
    }
    for (int bI = 0; bI < nfull; ++bI) {
        unsigned int v[8];
#pragma unroll
        for (int q = 0; q < 8; ++q) v[q] = xp[(cc[q].x << 6) | lane];
        // prefetch next csr batch (dummy re-read of jb on the last iteration)
        uint2 cn[8];
        {
            int jn = (bI + 1 < nfull) ? (j + 8) : jb;
            int ju = __builtin_amdgcn_readfirstlane(jn);
#pragma unroll
            for (int q = 0; q < 8; ++q) cn[q] = csr[ju + q];
        }
#pragma unroll
        for (int q = 0; q < 8; ++q) {
            float w0 = bf_lo(cc[q].y), w1 = bf_hi(cc[q].y);
            D0 += w0; D1 += w1;
            S0 = fmaf(w0, bf_lo(v[q]), S0);
            S1 = fmaf(w1, bf_hi(v[q]), S1);
        }
#pragma unroll
        for (int q = 0; q < 8; ++q) cc[q] = cn[q];
        j += 8;
    }
    for (; j + 3 < je; j += 4) {
        int ju = __builtin_amdgcn_readfirstlane(j);
        uint2 c[4];
#pragma unroll
        for (int q = 0; q < 4; ++q) c[q] = csr[ju + q];
        unsigned int v[4];
#pragma unroll
        for (int q = 0; q < 4; ++q) v[q] = xp[(c[q].x << 6) | lane];
#pragma unroll
        for (int q = 0; q < 4; ++q) {
            float w0 = bf_lo(c[q].y), w1 = bf_hi(c[q].y);
            D0 += w0; D1 += w1;
            S0 = fmaf(w0, bf_lo(v[q]), S0);
            S1 = fmaf(w1, bf_hi(v[q]), S1);
        }
    }
    for (; j < je; ++j) {
        uint2 c = csr[__builtin_amdgcn_readfirstlane(j)];
        unsigned int vv = xp[(c.x << 6) | lane];
        float w0 = bf_lo(c.y), w1 = bf_hi(c.y);
        D0 += w0; D1 += w1;
        S0 = fmaf(w0, bf_lo(vv), S0);
        S1 = fmaf(w1, bf_hi(vv), S1);
    }

    float o = (0.5f / (D0 + SM_EPS)) * S0 + (0.5f / (D1 + SM_EPS)) * S1 + bias[lane];

    float mu = o;
#pragma unroll
    for (int d = 32; d > 0; d >>= 1) mu += __shfl_xor(mu, d);
    mu *= (1.0f / 64.0f);
    float dv = o - mu;
    float var = dv * dv;
#pragma unroll
    for (int d = 32; d > 0; d >>= 1) var += __shfl_xor(var, d);
    var *= (1.0f / 64.0f);
    out[(size_t)n * 64 + lane] = dv * rsqrtf(var + LN_EPS) * gamma[lane] + beta[lane];
}

// ---------------------------------------------------------------------------
extern "C" void kernel_launch(void* const* d_in, const int* in_sizes, int n_in,
                              void* d_out, int out_size, void* d_ws, size_t ws_size,
                              hipStream_t stream) {
    const float* X        = (const float*)d_in[0];
    const int*   ei       = (const int*)d_in[1];
    const float* W        = (const float*)d_in[2];
    const float* att_src  = (const float*)d_in[3];
    const float* att_dst  = (const float*)d_in[4];
    const float* bias     = (const float*)d_in[5];
    const float* ln_gamma = (const float*)d_in[6];
    const float* ln_beta  = (const float*)d_in[7];
    float* out = (float*)d_out;

    const int N = in_sizes[0] / 128;
    const int E = in_sizes[1] / 2;
    const int NBUCK = (N + 255) / 256;
    const int SB = (E + SCHUNK - 1) / SCHUNK;
    const int GB = (N + 63) / 64;

    char* ws = (char*)d_ws;
    size_t off = 0;
    auto alloc = [&](size_t bytes) {
        size_t o = off;
        off += (bytes + 255) & ~(size_t)255;
        return o;
    };
    unsigned int* xp     = (unsigned int*)(ws + alloc((size_t)N * 64 * 4));
    float4* PS           = (float4*)(ws + alloc((size_t)N * 16));
    float4* PD           = (float4*)(ws + alloc((size_t)N * 16));
    unsigned int* rowPtr = (unsigned int*)(ws + alloc((size_t)N * 4));
    uint2* csr           = (uint2*)(ws + alloc((size_t)NBIN * BCAP * 8));
    unsigned int* tmp    = (unsigned int*)(ws + alloc((size_t)NBIN * BCAP * 4));
    int* binCursor       = (int*)(ws + alloc(NBIN * CURPAD * 4));

    hipMemsetAsync(binCursor, 0, (size_t)NBIN * CURPAD * 4, stream);
    k_gs<<<SB + GB, 256, 0, stream>>>(X, W, att_src, att_dst, xp, PS, PD,
                                      ei, binCursor, tmp, N, E, SB);
    k_bucket<<<NBUCK, 512, 0, stream>>>(tmp, binCursor, PS, PD, csr, rowPtr, N);
    k_agg<<<(N + 3) / 4, 256, 0, stream>>>(xp, PS, PD, rowPtr, csr,
                                           bias, ln_gamma, ln_beta, out, N);
}

// Round 12
// 219.563 us; speedup vs baseline: 1.1751x; 1.0125x over previous
//
#include <hip/hip_runtime.h>
#include <hip/hip_bf16.h>

#define NEG_SLOPE 0.2f
#define LN_EPS 1e-5f
#define SM_EPS 1e-16f

typedef __attribute__((ext_vector_type(8))) short bf16x8;
typedef __attribute__((ext_vector_type(4))) float f32x4;

__device__ inline unsigned short f2bf(float f) {
    unsigned u = __float_as_uint(f);
    return (unsigned short)((u + 0x7FFFu + ((u >> 16) & 1u)) >> 16);
}
__device__ inline float bf_lo(unsigned int v) { return __uint_as_float(v << 16); }
__device__ inline float bf_hi(unsigned int v) { return __uint_as_float(v & 0xffff0000u); }

#define NBIN 512           // bins = dst>>8 (256 dsts per bin); ~391 occupied at N=100k
#define BCAP 4864          // slots per bin: mean E/391 ~= 4092, sigma ~64 -> +12 sigma
#define SCHUNK 4096        // edges per scatter block (16/thread)
#define CURPAD 16          // binCursor stride in ints -> one counter per 64B line

// ---------------------------------------------------------------------------
// k_gs: heterogeneous fused dispatch. Blocks [0,SB) run the scatter body
// (reads ei only), blocks [SB,SB+GB) run the GEMM body (reads X,W only).
// GEMM epilogue stores factorized attention weights:
//   PS[n] = {e^aS0, e^(0.2 aS0), e^aS1, e^(0.2 aS1)}, PD[n] likewise, so
// downstream weight eval is exp-free: exp(leaky(aS+aD)) == (eS*eD >= 1)
// ? eS*eD : eSp*eDp. binCursor bin-RELATIVE, init by hipMemsetAsync.
// ---------------------------------------------------------------------------
__global__ __launch_bounds__(256) void k_gs(const float* __restrict__ X,
                                            const float* __restrict__ W,
                                            const float* __restrict__ att_src,
                                            const float* __restrict__ att_dst,
                                            unsigned int* __restrict__ xp,
                                            float4* __restrict__ PS,
                                            float4* __restrict__ PD,
                                            const int* __restrict__ ei,
                                            int* __restrict__ binCursor,
                                            unsigned int* __restrict__ tmp,
                                            int N, int E, int SB) {
    __shared__ __align__(16) char smem[52224];
    const int t = threadIdx.x;

    if ((int)blockIdx.x < SB) {
        // ---------------- scatter body: pure streaming binner ----------------
        int* off = (int*)smem;
        const int base = blockIdx.x * SCHUNK;

        int bn[16];
        unsigned int pe[16];
#pragma unroll
        for (int k = 0; k < 16; ++k) {
            int i = base + k * 256 + t;
            if (i < E) {
                int s = ei[i];
                int d = ei[E + i];
                bn[k] = d >> 8;
                pe[k] = ((unsigned)(d & 255) << 24) | (unsigned)s;
            } else {
                bn[k] = -1;
            }
        }

        for (int i = t; i < NBIN; i += 256) off[i] = 0;
        __syncthreads();
#pragma unroll
        for (int k = 0; k < 16; ++k)
            if (bn[k] >= 0) atomicAdd(&off[bn[k]], 1);
        __syncthreads();
        for (int i = t; i < NBIN; i += 256) {
            int h = off[i];
            off[i] = h ? (atomicAdd(&binCursor[i * CURPAD], h) + i * BCAP) : 0;
        }
        __syncthreads();
#pragma unroll
        for (int k = 0; k < 16; ++k) {
            if (bn[k] >= 0) {
                int p = atomicAdd(&off[bn[k]], 1);
                tmp[p] = pe[k];
            }
        }
        return;
    }

    // ---------------- GEMM body: bf16 MFMA + attention dots ----------------
    unsigned short* Ws = (unsigned short*)smem;                 // 128*136 ushort
    unsigned short* Xs = (unsigned short*)(smem + 34816);       //  64*136 ushort
    const int b0 = ((int)blockIdx.x - SB) * 64;
    const int lane = t & 63;
    const int w = t >> 6;
    const int c15 = lane & 15;
    const int quad = lane >> 4;

#pragma unroll
    for (int i = 0; i < 16; ++i) {
        int f = i * 256 + t;
        int nr = f >> 5;
        int q = f & 31;
        float4 v = reinterpret_cast<const float4*>(W)[nr * 32 + q];
        ushort4 b;
        b.x = f2bf(v.x); b.y = f2bf(v.y); b.z = f2bf(v.z); b.w = f2bf(v.w);
        *reinterpret_cast<ushort4*>(&Ws[nr * 136 + q * 4]) = b;
    }
#pragma unroll
    for (int i = 0; i < 8; ++i) {
        int f = i * 256 + t;
        int m = f >> 5;
        int q = f & 31;
        int gr = b0 + m;
        if (gr >= N) gr = N - 1;
        float4 v = reinterpret_cast<const float4*>(X)[(size_t)gr * 32 + q];
        ushort4 b;
        b.x = f2bf(v.x); b.y = f2bf(v.y); b.z = f2bf(v.z); b.w = f2bf(v.w);
        *reinterpret_cast<ushort4*>(&Xs[m * 136 + q * 4]) = b;
    }
    __syncthreads();

    f32x4 acc[8];
#pragma unroll
    for (int ct = 0; ct < 8; ++ct) acc[ct] = (f32x4){0.f, 0.f, 0.f, 0.f};

#pragma unroll
    for (int kc = 0; kc < 4; ++kc) {
        bf16x8 af = *reinterpret_cast<const bf16x8*>(
            &Xs[(w * 16 + c15) * 136 + kc * 32 + quad * 8]);
#pragma unroll
        for (int ct = 0; ct < 8; ++ct) {
            bf16x8 bfr = *reinterpret_cast<const bf16x8*>(
                &Ws[(ct * 16 + c15) * 136 + kc * 32 + quad * 8]);
            acc[ct] = __builtin_amdgcn_mfma_f32_16x16x32_bf16(af, bfr, acc[ct], 0, 0, 0);
        }
    }

    float attS[8], attD[8];
#pragma unroll
    for (int ct = 0; ct < 8; ++ct) {
        attS[ct] = att_src[ct * 16 + c15];
        attD[ct] = att_dst[ct * 16 + c15];
    }

#pragma unroll
    for (int r = 0; r < 4; ++r) {
        int row = b0 + w * 16 + quad * 4 + r;
        float s0 = 0.f, s1 = 0.f, d0 = 0.f, d1 = 0.f;
#pragma unroll
        for (int ct = 0; ct < 4; ++ct) {
            s0 += acc[ct][r] * attS[ct];
            d0 += acc[ct][r] * attD[ct];
            s1 += acc[ct + 4][r] * attS[ct + 4];
            d1 += acc[ct + 4][r] * attD[ct + 4];
        }
#pragma unroll
        for (int o = 1; o < 16; o <<= 1) {
            s0 += __shfl_xor(s0, o);
            s1 += __shfl_xor(s1, o);
            d0 += __shfl_xor(d0, o);
            d1 += __shfl_xor(d1, o);
        }
        if (row < N) {
#pragma unroll
            for (int ct = 0; ct < 4; ++ct) {
                unsigned int p = (unsigned int)f2bf(acc[ct][r]) |
                                 ((unsigned int)f2bf(acc[ct + 4][r]) << 16);
                xp[(size_t)row * 64 + ct * 16 + c15] = p;
            }
            if (c15 == 0) {
                PS[row] = make_float4(__expf(s0), __expf(NEG_SLOPE * s0),
                                      __expf(s1), __expf(NEG_SLOPE * s1));
                PD[row] = make_float4(__expf(d0), __expf(NEG_SLOPE * d0),
                                      __expf(d1), __expf(NEG_SLOPE * d1));
            }
        }
    }
}

// ---------------------------------------------------------------------------
// k_bucket: one block per 256-dst bin, 1024 threads (was 512: P2's per-edge
// chain {tmp read -> PS gather -> LDS cursor atomic -> scattered 8B write}
// is pure latency with ~zero VALU; 391 blocks x 16 waves = 6256 waves
// doubles the TLP hiding it; R9 showed 1024t is safe when per-edge work is
// light — its cost was den atomics + metaN, both absent here).
// P1: cnt histogram (1 LDS atomic/edge). Scan -> packed rowPtr
// {beg|cnt<<22}. P2: re-read tmp (L2-hot), gather PS[src] (L2-hot 1.6MB),
// factorized exp-free weight u01, counting-sort write of csr uint2
// {src,u01}. Denominators accumulate in k_agg.
// ---------------------------------------------------------------------------
__global__ __launch_bounds__(1024) void k_bucket(const unsigned int* __restrict__ tmp,
                                                 const int* __restrict__ binCursor,
                                                 const float4* __restrict__ PS,
                                                 const float4* __restrict__ PD,
                                                 uint2* __restrict__ csr,
                                                 unsigned int* __restrict__ rowPtr,
                                                 int N) {
    __shared__ int cnt[256];
    __shared__ int cur[256];
    __shared__ int lds[4];
    __shared__ float4 pdc[256];
    const int t = threadIdx.x;
    const int b = blockIdx.x;
    const int start = b * BCAP;
    const int d0 = b * 256;
    int m = binCursor[b * CURPAD];
    if (m > BCAP) m = BCAP;   // statistically unreachable guard

    if (t < 256) {
        cnt[t] = 0;
        int d = d0 + t;
        pdc[t] = (d < N) ? PD[d] : make_float4(0.f, 0.f, 0.f, 0.f);
    }
    __syncthreads();

    for (int k = t; k < m; k += 1024) {
        atomicAdd(&cnt[tmp[start + k] >> 24], 1);
    }
    __syncthreads();

    const int lane = t & 63, w = t >> 6;
    int v = 0, incl = 0;
    if (t < 256) {                 // waves 0-3 fully active -> shfl safe
        v = cnt[t];
        incl = v;
#pragma unroll
        for (int o = 1; o < 64; o <<= 1) {
            int u = __shfl_up(incl, o);
            if (lane >= o) incl += u;
        }
        if (lane == 63) lds[w] = incl;
    }
    __syncthreads();
    if (t == 0) {
        int run = 0;
        for (int i = 0; i < 4; ++i) { int tv = lds[i]; lds[i] = run; run += tv; }
    }
    __syncthreads();
    if (t < 256) {
        int excl = lds[w] + incl - v;
        cur[t] = excl;
        int d = d0 + t;
        if (d < N) rowPtr[d] = (unsigned)(start + excl) | ((unsigned)v << 22);
    }
    __syncthreads();

    // P2: weight + counting-sort placement
    for (int k = t; k < m; k += 1024) {
        unsigned int e = tmp[start + k];
        int li = e >> 24;
        int s = (int)(e & 0x00FFFFFFu);
        float4 ps = PS[s];
        float4 pd = pdc[li];
        float m0 = ps.x * pd.x, mp0 = ps.y * pd.y;
        float m1 = ps.z * pd.z, mp1 = ps.w * pd.w;
        float u0 = fmaxf(m0, mp0);   // == (m0>=1 ? m0 : mp0): both cross 1 together
        float u1 = fmaxf(m1, mp1);
        unsigned int u01;
        asm("v_cvt_pk_bf16_f32 %0, %1, %2" : "=v"(u01) : "v"(u0), "v"(u1));
        int p = atomicAdd(&cur[li], 1);
        csr[start + p] = make_uint2((unsigned)s, u01);
    }
}

// ---------------------------------------------------------------------------
// K5: per-dst aggregation + bias + LayerNorm — single-dst champion structure
// (rounds 9/11: 64-65us @ 42-68% VALU; round-10 lesson: 2-dst pairing
// doubles per-wave state and wastes clamp gathers -> never again).
// Weights arrive packed in csr uint2 via uniform (readfirstlane-addressed)
// loads -> SGPRs; unpack is SALU; inner loop = 2 FMA + 2 den-adds per edge.
// Self weight from uniform PS[n]/PD[n] (exp-free factorization). 32-bit xp
// addressing. Next csr batch prefetched while gathers + FMAs run.
// ---------------------------------------------------------------------------
__global__ __launch_bounds__(256) void k_agg(const unsigned int* __restrict__ xp,
                                             const float4* __restrict__ PS,
                                             const float4* __restrict__ PD,
                                             const unsigned int* __restrict__ rowPtr,
                                             const uint2* __restrict__ csr,
                                             const float* __restrict__ bias,
                                             const float* __restrict__ gamma,
                                             const float* __restrict__ beta,
                                             float* __restrict__ out, int N) {
    const int w = threadIdx.x >> 6, lane = threadIdx.x & 63;
    const int n = blockIdx.x * 4 + w;
    if (n >= N) return;

    // self weight from factorized exps (f32, unquantized)
    float4 ps = PS[n], pd = PD[n];
    float us0 = fmaxf(ps.x * pd.x, ps.y * pd.y);
    float us1 = fmaxf(ps.z * pd.z, ps.w * pd.w);

    unsigned int vself = xp[((unsigned)n << 6) | lane];
    float S0 = us0 * bf_lo(vself);
    float S1 = us1 * bf_hi(vself);
    float D0 = us0, D1 = us1;

    unsigned int pr = rowPtr[n];
    const int jb = (int)(pr & 0x3FFFFFu);
    const int je = jb + (int)(pr >> 22);
    int j = jb;
    const int nfull = (je - jb) >> 3;

    uint2 cc[8];
    if (nfull > 0) {
        int ju = __builtin_amdgcn_readfirstlane(j);
#pragma unroll
        for (int q = 0; q < 8; ++q) cc[q] = csr[ju + q];
    }
    for (int bI = 0; bI < nfull; ++bI) {
        unsigned int v[8];
#pragma unroll
        for (int q = 0; q < 8; ++q) v[q] = xp[(cc[q].x << 6) | lane];
        // prefetch next csr batch (dummy re-read of jb on the last iteration)
        uint2 cn[8];
        {
            int jn = (bI + 1 < nfull) ? (j + 8) : jb;
            int ju = __builtin_amdgcn_readfirstlane(jn);
#pragma unroll
            for (int q = 0; q < 8; ++q) cn[q] = csr[ju + q];
        }
#pragma unroll
        for (int q = 0; q < 8; ++q) {
            float w0 = bf_lo(cc[q].y), w1 = bf_hi(cc[q].y);
            D0 += w0; D1 += w1;
            S0 = fmaf(w0, bf_lo(v[q]), S0);
            S1 = fmaf(w1, bf_hi(v[q]), S1);
        }
#pragma unroll
        for (int q = 0; q < 8; ++q) cc[q] = cn[q];
        j += 8;
    }
    for (; j + 3 < je; j += 4) {
        int ju = __builtin_amdgcn_readfirstlane(j);
        uint2 c[4];
#pragma unroll
        for (int q = 0; q < 4; ++q) c[q] = csr[ju + q];
        unsigned int v[4];
#pragma unroll
        for (int q = 0; q < 4; ++q) v[q] = xp[(c[q].x << 6) | lane];
#pragma unroll
        for (int q = 0; q < 4; ++q) {
            float w0 = bf_lo(c[q].y), w1 = bf_hi(c[q].y);
            D0 += w0; D1 += w1;
            S0 = fmaf(w0, bf_lo(v[q]), S0);
            S1 = fmaf(w1, bf_hi(v[q]), S1);
        }
    }
    for (; j < je; ++j) {
        uint2 c = csr[__builtin_amdgcn_readfirstlane(j)];
        unsigned int vv = xp[(c.x << 6) | lane];
        float w0 = bf_lo(c.y), w1 = bf_hi(c.y);
        D0 += w0; D1 += w1;
        S0 = fmaf(w0, bf_lo(vv), S0);
        S1 = fmaf(w1, bf_hi(vv), S1);
    }

    float o = (0.5f / (D0 + SM_EPS)) * S0 + (0.5f / (D1 + SM_EPS)) * S1 + bias[lane];

    float mu = o;
#pragma unroll
    for (int d = 32; d > 0; d >>= 1) mu += __shfl_xor(mu, d);
    mu *= (1.0f / 64.0f);
    float dv = o - mu;
    float var = dv * dv;
#pragma unroll
    for (int d = 32; d > 0; d >>= 1) var += __shfl_xor(var, d);
    var *= (1.0f / 64.0f);
    out[(size_t)n * 64 + lane] = dv * rsqrtf(var + LN_EPS) * gamma[lane] + beta[lane];
}

// ---------------------------------------------------------------------------
extern "C" void kernel_launch(void* const* d_in, const int* in_sizes, int n_in,
                              void* d_out, int out_size, void* d_ws, size_t ws_size,
                              hipStream_t stream) {
    const float* X        = (const float*)d_in[0];
    const int*   ei       = (const int*)d_in[1];
    const float* W        = (const float*)d_in[2];
    const float* att_src  = (const float*)d_in[3];
    const float* att_dst  = (const float*)d_in[4];
    const float* bias     = (const float*)d_in[5];
    const float* ln_gamma = (const float*)d_in[6];
    const float* ln_beta  = (const float*)d_in[7];
    float* out = (float*)d_out;

    const int N = in_sizes[0] / 128;
    const int E = in_sizes[1] / 2;
    const int NBUCK = (N + 255) / 256;
    const int SB = (E + SCHUNK - 1) / SCHUNK;
    const int GB = (N + 63) / 64;

    char* ws = (char*)d_ws;
    size_t off = 0;
    auto alloc = [&](size_t bytes) {
        size_t o = off;
        off += (bytes + 255) & ~(size_t)255;
        return o;
    };
    unsigned int* xp     = (unsigned int*)(ws + alloc((size_t)N * 64 * 4));
    float4* PS           = (float4*)(ws + alloc((size_t)N * 16));
    float4* PD           = (float4*)(ws + alloc((size_t)N * 16));
    unsigned int* rowPtr = (unsigned int*)(ws + alloc((size_t)N * 4));
    uint2* csr           = (uint2*)(ws + alloc((size_t)NBIN * BCAP * 8));
    unsigned int* tmp    = (unsigned int*)(ws + alloc((size_t)NBIN * BCAP * 4));
    int* binCursor       = (int*)(ws + alloc(NBIN * CURPAD * 4));

    hipMemsetAsync(binCursor, 0, (size_t)NBIN * CURPAD * 4, stream);
    k_gs<<<SB + GB, 256, 0, stream>>>(X, W, att_src, att_dst, xp, PS, PD,
                                      ei, binCursor, tmp, N, E, SB);
    k_bucket<<<NBUCK, 1024, 0, stream>>>(tmp, binCursor, PS, PD, csr, rowPtr, N);
    k_agg<<<(N + 3) / 4, 256, 0, stream>>>(xp, PS, PD, rowPtr, csr,
                                           bias, ln_gamma, ln_beta, out, N);
}

// Round 13
// 216.558 us; speedup vs baseline: 1.1914x; 1.0139x over previous
//
#include <hip/hip_runtime.h>
#include <hip/hip_bf16.h>

#define NEG_SLOPE 0.2f
#define LN_EPS 1e-5f
#define SM_EPS 1e-16f

typedef __attribute__((ext_vector_type(8))) short bf16x8;
typedef __attribute__((ext_vector_type(4))) float f32x4;

__device__ inline float bf_lo(unsigned int v) { return __uint_as_float(v << 16); }
__device__ inline float bf_hi(unsigned int v) { return __uint_as_float(v & 0xffff0000u); }
__device__ inline unsigned int pk_bf16(float lo, float hi) {
    unsigned int r;
    asm("v_cvt_pk_bf16_f32 %0, %1, %2" : "=v"(r) : "v"(lo), "v"(hi));
    return r;
}

#define NBIN 512           // bins = dst>>8 (256 dsts per bin); ~391 occupied at N=100k
#define BCAP 4864          // slots per bin: mean E/391 ~= 4092, sigma ~64 -> +12 sigma
#define SCHUNK 4096        // edges per scatter block (16/thread)
#define CURPAD 16          // binCursor stride in ints -> one counter per 64B line

// ---------------------------------------------------------------------------
// k_gs: heterogeneous fused dispatch. Blocks [0,SB) run the scatter body
// (reads ei only), blocks [SB,SB+GB) run the GEMM body (reads X,W only).
// bf16 conversion now via v_cvt_pk_bf16_f32 (1 inst / 2 floats) instead of
// ~4-VALU scalar f2bf — staging was the gemm body's VALU hot spot (~96
// conversions/thread). GEMM epilogue stores factorized attention weights:
//   PS[n] = {e^aS0, e^(0.2 aS0), e^aS1, e^(0.2 aS1)}, PD[n] likewise, so
// downstream weight eval is exp-free: exp(leaky(aS+aD)) ==
// max(eS*eD, eSp*eDp) (both products cross 1 at the same point).
// binCursor bin-RELATIVE, init by hipMemsetAsync.
// ---------------------------------------------------------------------------
__global__ __launch_bounds__(256) void k_gs(const float* __restrict__ X,
                                            const float* __restrict__ W,
                                            const float* __restrict__ att_src,
                                            const float* __restrict__ att_dst,
                                            unsigned int* __restrict__ xp,
                                            float4* __restrict__ PS,
                                            float4* __restrict__ PD,
                                            const int* __restrict__ ei,
                                            int* __restrict__ binCursor,
                                            unsigned int* __restrict__ tmp,
                                            int N, int E, int SB) {
    __shared__ __align__(16) char smem[52224];
    const int t = threadIdx.x;

    if ((int)blockIdx.x < SB) {
        // ---------------- scatter body: pure streaming binner ----------------
        int* off = (int*)smem;
        const int base = blockIdx.x * SCHUNK;

        int bn[16];
        unsigned int pe[16];
#pragma unroll
        for (int k = 0; k < 16; ++k) {
            int i = base + k * 256 + t;
            if (i < E) {
                int s = ei[i];
                int d = ei[E + i];
                bn[k] = d >> 8;
                pe[k] = ((unsigned)(d & 255) << 24) | (unsigned)s;
            } else {
                bn[k] = -1;
            }
        }

        for (int i = t; i < NBIN; i += 256) off[i] = 0;
        __syncthreads();
#pragma unroll
        for (int k = 0; k < 16; ++k)
            if (bn[k] >= 0) atomicAdd(&off[bn[k]], 1);
        __syncthreads();
        for (int i = t; i < NBIN; i += 256) {
            int h = off[i];
            off[i] = h ? (atomicAdd(&binCursor[i * CURPAD], h) + i * BCAP) : 0;
        }
        __syncthreads();
#pragma unroll
        for (int k = 0; k < 16; ++k) {
            if (bn[k] >= 0) {
                int p = atomicAdd(&off[bn[k]], 1);
                tmp[p] = pe[k];
            }
        }
        return;
    }

    // ---------------- GEMM body: bf16 MFMA + attention dots ----------------
    unsigned short* Ws = (unsigned short*)smem;                 // 128*136 ushort
    unsigned short* Xs = (unsigned short*)(smem + 34816);       //  64*136 ushort
    const int b0 = ((int)blockIdx.x - SB) * 64;
    const int lane = t & 63;
    const int w = t >> 6;
    const int c15 = lane & 15;
    const int quad = lane >> 4;

#pragma unroll
    for (int i = 0; i < 16; ++i) {
        int f = i * 256 + t;
        int nr = f >> 5;
        int q = f & 31;
        float4 v = reinterpret_cast<const float4*>(W)[nr * 32 + q];
        // rows are 272B (8B-aligned), q*4 ushorts = 8B steps -> uint2 store ok
        *reinterpret_cast<uint2*>(&Ws[nr * 136 + q * 4]) =
            make_uint2(pk_bf16(v.x, v.y), pk_bf16(v.z, v.w));
    }
#pragma unroll
    for (int i = 0; i < 8; ++i) {
        int f = i * 256 + t;
        int m = f >> 5;
        int q = f & 31;
        int gr = b0 + m;
        if (gr >= N) gr = N - 1;
        float4 v = reinterpret_cast<const float4*>(X)[(size_t)gr * 32 + q];
        *reinterpret_cast<uint2*>(&Xs[m * 136 + q * 4]) =
            make_uint2(pk_bf16(v.x, v.y), pk_bf16(v.z, v.w));
    }
    __syncthreads();

    f32x4 acc[8];
#pragma unroll
    for (int ct = 0; ct < 8; ++ct) acc[ct] = (f32x4){0.f, 0.f, 0.f, 0.f};

#pragma unroll
    for (int kc = 0; kc < 4; ++kc) {
        bf16x8 af = *reinterpret_cast<const bf16x8*>(
            &Xs[(w * 16 + c15) * 136 + kc * 32 + quad * 8]);
#pragma unroll
        for (int ct = 0; ct < 8; ++ct) {
            bf16x8 bfr = *reinterpret_cast<const bf16x8*>(
                &Ws[(ct * 16 + c15) * 136 + kc * 32 + quad * 8]);
            acc[ct] = __builtin_amdgcn_mfma_f32_16x16x32_bf16(af, bfr, acc[ct], 0, 0, 0);
        }
    }

    float attS[8], attD[8];
#pragma unroll
    for (int ct = 0; ct < 8; ++ct) {
        attS[ct] = att_src[ct * 16 + c15];
        attD[ct] = att_dst[ct * 16 + c15];
    }

#pragma unroll
    for (int r = 0; r < 4; ++r) {
        int row = b0 + w * 16 + quad * 4 + r;
        float s0 = 0.f, s1 = 0.f, d0 = 0.f, d1 = 0.f;
#pragma unroll
        for (int ct = 0; ct < 4; ++ct) {
            s0 += acc[ct][r] * attS[ct];
            d0 += acc[ct][r] * attD[ct];
            s1 += acc[ct + 4][r] * attS[ct + 4];
            d1 += acc[ct + 4][r] * attD[ct + 4];
        }
#pragma unroll
        for (int o = 1; o < 16; o <<= 1) {
            s0 += __shfl_xor(s0, o);
            s1 += __shfl_xor(s1, o);
            d0 += __shfl_xor(d0, o);
            d1 += __shfl_xor(d1, o);
        }
        if (row < N) {
#pragma unroll
            for (int ct = 0; ct < 4; ++ct) {
                xp[(size_t)row * 64 + ct * 16 + c15] =
                    pk_bf16(acc[ct][r], acc[ct + 4][r]);
            }
            if (c15 == 0) {
                PS[row] = make_float4(__expf(s0), __expf(NEG_SLOPE * s0),
                                      __expf(s1), __expf(NEG_SLOPE * s1));
                PD[row] = make_float4(__expf(d0), __expf(NEG_SLOPE * d0),
                                      __expf(d1), __expf(NEG_SLOPE * d1));
            }
        }
    }
}

// ---------------------------------------------------------------------------
// k_bucket: one block per 256-dst bin, 1024 threads (R12: -3us vs 512).
// P1: cnt histogram (1 LDS atomic/edge). Scan -> packed rowPtr
// {beg|cnt<<22}. P2: re-read tmp (L2-hot), gather PS[src] (L2-hot 1.6MB),
// factorized exp-free weight u01 = max-form, counting-sort write of csr
// uint2 {src,u01}. Denominators accumulate in k_agg.
// ---------------------------------------------------------------------------
__global__ __launch_bounds__(1024) void k_bucket(const unsigned int* __restrict__ tmp,
                                                 const int* __restrict__ binCursor,
                                                 const float4* __restrict__ PS,
                                                 const float4* __restrict__ PD,
                                                 uint2* __restrict__ csr,
                                                 unsigned int* __restrict__ rowPtr,
                                                 int N) {
    __shared__ int cnt[256];
    __shared__ int cur[256];
    __shared__ int lds[4];
    __shared__ float4 pdc[256];
    const int t = threadIdx.x;
    const int b = blockIdx.x;
    const int start = b * BCAP;
    const int d0 = b * 256;
    int m = binCursor[b * CURPAD];
    if (m > BCAP) m = BCAP;   // statistically unreachable guard

    if (t < 256) {
        cnt[t] = 0;
        int d = d0 + t;
        pdc[t] = (d < N) ? PD[d] : make_float4(0.f, 0.f, 0.f, 0.f);
    }
    __syncthreads();

    for (int k = t; k < m; k += 1024) {
        atomicAdd(&cnt[tmp[start + k] >> 24], 1);
    }
    __syncthreads();

    const int lane = t & 63, w = t >> 6;
    int v = 0, incl = 0;
    if (t < 256) {                 // waves 0-3 fully active -> shfl safe
        v = cnt[t];
        incl = v;
#pragma unroll
        for (int o = 1; o < 64; o <<= 1) {
            int u = __shfl_up(incl, o);
            if (lane >= o) incl += u;
        }
        if (lane == 63) lds[w] = incl;
    }
    __syncthreads();
    if (t == 0) {
        int run = 0;
        for (int i = 0; i < 4; ++i) { int tv = lds[i]; lds[i] = run; run += tv; }
    }
    __syncthreads();
    if (t < 256) {
        int excl = lds[w] + incl - v;
        cur[t] = excl;
        int d = d0 + t;
        if (d < N) rowPtr[d] = (unsigned)(start + excl) | ((unsigned)v << 22);
    }
    __syncthreads();

    // P2: weight + counting-sort placement
    for (int k = t; k < m; k += 1024) {
        unsigned int e = tmp[start + k];
        int li = e >> 24;
        int s = (int)(e & 0x00FFFFFFu);
        float4 ps = PS[s];
        float4 pd = pdc[li];
        float u0 = fmaxf(ps.x * pd.x, ps.y * pd.y);
        float u1 = fmaxf(ps.z * pd.z, ps.w * pd.w);
        int p = atomicAdd(&cur[li], 1);
        csr[start + p] = make_uint2((unsigned)s, pk_bf16(u0, u1));
    }
}

// ---------------------------------------------------------------------------
// K5: per-dst aggregation + bias + LayerNorm — single-dst champion structure
// (rounds 9/11/12: 64-65us; round-10 lesson: no dst-pairing). Weights
// arrive packed in csr uint2 via uniform (readfirstlane-addressed) loads ->
// SGPRs; unpack is SALU; inner loop = 2 FMA + 2 den-adds per edge. Tail
// loops replaced by a masked final batch (indices clamped to last, weights
// zeroed by uniform select for q >= limit — R7-proven): all 8 tail gathers
// fly in parallel instead of serial scalar iterations; overshoot gathers
// re-hit the last edge's L1-hot row. Self weight from uniform PS[n]/PD[n].
// ---------------------------------------------------------------------------
__global__ __launch_bounds__(256) void k_agg(const unsigned int* __restrict__ xp,
                                             const float4* __restrict__ PS,
                                             const float4* __restrict__ PD,
                                             const unsigned int* __restrict__ rowPtr,
                                             const uint2* __restrict__ csr,
                                             const float* __restrict__ bias,
                                             const float* __restrict__ gamma,
                                             const float* __restrict__ beta,
                                             float* __restrict__ out, int N) {
    const int w = threadIdx.x >> 6, lane = threadIdx.x & 63;
    const int n = blockIdx.x * 4 + w;
    if (n >= N) return;

    // self weight from factorized exps (f32, unquantized)
    float4 ps = PS[n], pd = PD[n];
    float us0 = fmaxf(ps.x * pd.x, ps.y * pd.y);
    float us1 = fmaxf(ps.z * pd.z, ps.w * pd.w);

    unsigned int vself = xp[((unsigned)n << 6) | lane];
    float S0 = us0 * bf_lo(vself);
    float S1 = us1 * bf_hi(vself);
    float D0 = us0, D1 = us1;

    unsigned int pr = rowPtr[n];
    const int jb = (int)(pr & 0x3FFFFFu);
    const int deg = (int)(pr >> 22);
    const int je = jb + deg;
    const int nb = (deg + 7) >> 3;
    const int last = (deg > 0) ? (je - 1) : jb;

    int j = jb;
    uint2 cc[8];
    if (nb > 0) {
        int ju = __builtin_amdgcn_readfirstlane(jb);
        int lu = __builtin_amdgcn_readfirstlane(last);
#pragma unroll
        for (int q = 0; q < 8; ++q) {
            int idx = ju + q; if (idx > lu) idx = lu;
            cc[q] = csr[idx];
        }
    }
    for (int bI = 0; bI < nb; ++bI) {
        const int limit = je - j;            // uniform; >=8 except last batch
        unsigned int v[8];
#pragma unroll
        for (int q = 0; q < 8; ++q) v[q] = xp[(cc[q].x << 6) | lane];
        // prefetch next batch's csr entries (re-read base on last iteration)
        uint2 cn[8];
        {
            int jn = (bI + 1 < nb) ? (j + 8) : jb;
            int ju = __builtin_amdgcn_readfirstlane(jn);
            int lu = __builtin_amdgcn_readfirstlane(last);
#pragma unroll
            for (int q = 0; q < 8; ++q) {
                int idx = ju + q; if (idx > lu) idx = lu;
                cn[q] = csr[idx];
            }
        }
#pragma unroll
        for (int q = 0; q < 8; ++q) {
            unsigned int uy = (q < limit) ? cc[q].y : 0u;   // uniform SALU select
            float w0 = bf_lo(uy), w1 = bf_hi(uy);
            D0 += w0; D1 += w1;
            S0 = fmaf(w0, bf_lo(v[q]), S0);
            S1 = fmaf(w1, bf_hi(v[q]), S1);
        }
#pragma unroll
        for (int q = 0; q < 8; ++q) cc[q] = cn[q];
        j += 8;
    }

    float o = (0.5f / (D0 + SM_EPS)) * S0 + (0.5f / (D1 + SM_EPS)) * S1 + bias[lane];

    float mu = o;
#pragma unroll
    for (int d = 32; d > 0; d >>= 1) mu += __shfl_xor(mu, d);
    mu *= (1.0f / 64.0f);
    float dv = o - mu;
    float var = dv * dv;
#pragma unroll
    for (int d = 32; d > 0; d >>= 1) var += __shfl_xor(var, d);
    var *= (1.0f / 64.0f);
    out[(size_t)n * 64 + lane] = dv * rsqrtf(var + LN_EPS) * gamma[lane] + beta[lane];
}

// ---------------------------------------------------------------------------
extern "C" void kernel_launch(void* const* d_in, const int* in_sizes, int n_in,
                              void* d_out, int out_size, void* d_ws, size_t ws_size,
                              hipStream_t stream) {
    const float* X        = (const float*)d_in[0];
    const int*   ei       = (const int*)d_in[1];
    const float* W        = (const float*)d_in[2];
    const float* att_src  = (const float*)d_in[3];
    const float* att_dst  = (const float*)d_in[4];
    const float* bias     = (const float*)d_in[5];
    const float* ln_gamma = (const float*)d_in[6];
    const float* ln_beta  = (const float*)d_in[7];
    float* out = (float*)d_out;

    const int N = in_sizes[0] / 128;
    const int E = in_sizes[1] / 2;
    const int NBUCK = (N + 255) / 256;
    const int SB = (E + SCHUNK - 1) / SCHUNK;
    const int GB = (N + 63) / 64;

    char* ws = (char*)d_ws;
    size_t off = 0;
    auto alloc = [&](size_t bytes) {
        size_t o = off;
        off += (bytes + 255) & ~(size_t)255;
        return o;
    };
    unsigned int* xp     = (unsigned int*)(ws + alloc((size_t)N * 64 * 4));
    float4* PS           = (float4*)(ws + alloc((size_t)N * 16));
    float4* PD           = (float4*)(ws + alloc((size_t)N * 16));
    unsigned int* rowPtr = (unsigned int*)(ws + alloc((size_t)N * 4));
    uint2* csr           = (uint2*)(ws + alloc((size_t)NBIN * BCAP * 8));
    unsigned int* tmp    = (unsigned int*)(ws + alloc((size_t)NBIN * BCAP * 4));
    int* binCursor       = (int*)(ws + alloc(NBIN * CURPAD * 4));

    hipMemsetAsync(binCursor, 0, (size_t)NBIN * CURPAD * 4, stream);
    k_gs<<<SB + GB, 256, 0, stream>>>(X, W, att_src, att_dst, xp, PS, PD,
                                      ei, binCursor, tmp, N, E, SB);
    k_bucket<<<NBUCK, 1024, 0, stream>>>(tmp, binCursor, PS, PD, csr, rowPtr, N);
    k_agg<<<(N + 3) / 4, 256, 0, stream>>>(xp, PS, PD, rowPtr, csr,
                                           bias, ln_gamma, ln_beta, out, N);
}

// Round 14
// 216.193 us; speedup vs baseline: 1.1934x; 1.0017x over previous
//
#include <hip/hip_runtime.h>
#include <hip/hip_bf16.h>

#define NEG_SLOPE 0.2f
#define LN_EPS 1e-5f
#define SM_EPS 1e-16f

typedef __attribute__((ext_vector_type(8))) short bf16x8;
typedef __attribute__((ext_vector_type(4))) float f32x4;

__device__ inline float bf_lo(unsigned int v) { return __uint_as_float(v << 16); }
__device__ inline float bf_hi(unsigned int v) { return __uint_as_float(v & 0xffff0000u); }
__device__ inline unsigned int pk_bf16(float lo, float hi) {
    unsigned int r;
    asm("v_cvt_pk_bf16_f32 %0, %1, %2" : "=v"(r) : "v"(lo), "v"(hi));
    return r;
}

#define NBIN 512           // bins = dst>>8 (256 dsts per bin); ~391 occupied at N=100k
#define BCAP 4864          // slots per bin: mean E/391 ~= 4092, sigma ~64 -> +12 sigma
#define SCHUNK 4096        // edges per scatter block (16/thread)
#define CURPAD 16          // binCursor stride in ints -> one counter per 64B line

// ---------------------------------------------------------------------------
// k_gs: heterogeneous fused dispatch. Blocks [0,SB) run the scatter body
// (reads ei only), blocks [SB,SB+GB) run the GEMM body (reads X,W only).
// bf16 conversion via v_cvt_pk_bf16_f32 (R13: ~8us saved vs scalar f2bf).
// GEMM epilogue stores factorized attention weights:
//   PS[n] = {e^aS0, e^(0.2 aS0), e^aS1, e^(0.2 aS1)}, PD[n] likewise, so
// downstream weight eval is exp-free: exp(leaky(aS+aD)) ==
// max(eS*eD, eSp*eDp) (both products cross 1 at the same point).
// binCursor bin-RELATIVE, init by hipMemsetAsync.
// ---------------------------------------------------------------------------
__global__ __launch_bounds__(256) void k_gs(const float* __restrict__ X,
                                            const float* __restrict__ W,
                                            const float* __restrict__ att_src,
                                            const float* __restrict__ att_dst,
                                            unsigned int* __restrict__ xp,
                                            float4* __restrict__ PS,
                                            float4* __restrict__ PD,
                                            const int* __restrict__ ei,
                                            int* __restrict__ binCursor,
                                            unsigned int* __restrict__ tmp,
                                            int N, int E, int SB) {
    __shared__ __align__(16) char smem[52224];
    const int t = threadIdx.x;

    if ((int)blockIdx.x < SB) {
        // ---------------- scatter body: pure streaming binner ----------------
        int* off = (int*)smem;
        const int base = blockIdx.x * SCHUNK;

        int bn[16];
        unsigned int pe[16];
#pragma unroll
        for (int k = 0; k < 16; ++k) {
            int i = base + k * 256 + t;
            if (i < E) {
                int s = ei[i];
                int d = ei[E + i];
                bn[k] = d >> 8;
                pe[k] = ((unsigned)(d & 255) << 24) | (unsigned)s;
            } else {
                bn[k] = -1;
            }
        }

        for (int i = t; i < NBIN; i += 256) off[i] = 0;
        __syncthreads();
#pragma unroll
        for (int k = 0; k < 16; ++k)
            if (bn[k] >= 0) atomicAdd(&off[bn[k]], 1);
        __syncthreads();
        for (int i = t; i < NBIN; i += 256) {
            int h = off[i];
            off[i] = h ? (atomicAdd(&binCursor[i * CURPAD], h) + i * BCAP) : 0;
        }
        __syncthreads();
#pragma unroll
        for (int k = 0; k < 16; ++k) {
            if (bn[k] >= 0) {
                int p = atomicAdd(&off[bn[k]], 1);
                tmp[p] = pe[k];
            }
        }
        return;
    }

    // ---------------- GEMM body: bf16 MFMA + attention dots ----------------
    unsigned short* Ws = (unsigned short*)smem;                 // 128*136 ushort
    unsigned short* Xs = (unsigned short*)(smem + 34816);       //  64*136 ushort
    const int b0 = ((int)blockIdx.x - SB) * 64;
    const int lane = t & 63;
    const int w = t >> 6;
    const int c15 = lane & 15;
    const int quad = lane >> 4;

#pragma unroll
    for (int i = 0; i < 16; ++i) {
        int f = i * 256 + t;
        int nr = f >> 5;
        int q = f & 31;
        float4 v = reinterpret_cast<const float4*>(W)[nr * 32 + q];
        // rows are 272B (8B-aligned), q*4 ushorts = 8B steps -> uint2 store ok
        *reinterpret_cast<uint2*>(&Ws[nr * 136 + q * 4]) =
            make_uint2(pk_bf16(v.x, v.y), pk_bf16(v.z, v.w));
    }
#pragma unroll
    for (int i = 0; i < 8; ++i) {
        int f = i * 256 + t;
        int m = f >> 5;
        int q = f & 31;
        int gr = b0 + m;
        if (gr >= N) gr = N - 1;
        float4 v = reinterpret_cast<const float4*>(X)[(size_t)gr * 32 + q];
        *reinterpret_cast<uint2*>(&Xs[m * 136 + q * 4]) =
            make_uint2(pk_bf16(v.x, v.y), pk_bf16(v.z, v.w));
    }
    __syncthreads();

    f32x4 acc[8];
#pragma unroll
    for (int ct = 0; ct < 8; ++ct) acc[ct] = (f32x4){0.f, 0.f, 0.f, 0.f};

#pragma unroll
    for (int kc = 0; kc < 4; ++kc) {
        bf16x8 af = *reinterpret_cast<const bf16x8*>(
            &Xs[(w * 16 + c15) * 136 + kc * 32 + quad * 8]);
#pragma unroll
        for (int ct = 0; ct < 8; ++ct) {
            bf16x8 bfr = *reinterpret_cast<const bf16x8*>(
                &Ws[(ct * 16 + c15) * 136 + kc * 32 + quad * 8]);
            acc[ct] = __builtin_amdgcn_mfma_f32_16x16x32_bf16(af, bfr, acc[ct], 0, 0, 0);
        }
    }

    float attS[8], attD[8];
#pragma unroll
    for (int ct = 0; ct < 8; ++ct) {
        attS[ct] = att_src[ct * 16 + c15];
        attD[ct] = att_dst[ct * 16 + c15];
    }

#pragma unroll
    for (int r = 0; r < 4; ++r) {
        int row = b0 + w * 16 + quad * 4 + r;
        float s0 = 0.f, s1 = 0.f, d0 = 0.f, d1 = 0.f;
#pragma unroll
        for (int ct = 0; ct < 4; ++ct) {
            s0 += acc[ct][r] * attS[ct];
            d0 += acc[ct][r] * attD[ct];
            s1 += acc[ct + 4][r] * attS[ct + 4];
            d1 += acc[ct + 4][r] * attD[ct + 4];
        }
#pragma unroll
        for (int o = 1; o < 16; o <<= 1) {
            s0 += __shfl_xor(s0, o);
            s1 += __shfl_xor(s1, o);
            d0 += __shfl_xor(d0, o);
            d1 += __shfl_xor(d1, o);
        }
        if (row < N) {
#pragma unroll
            for (int ct = 0; ct < 4; ++ct) {
                xp[(size_t)row * 64 + ct * 16 + c15] =
                    pk_bf16(acc[ct][r], acc[ct + 4][r]);
            }
            if (c15 == 0) {
                PS[row] = make_float4(__expf(s0), __expf(NEG_SLOPE * s0),
                                      __expf(s1), __expf(NEG_SLOPE * s1));
                PD[row] = make_float4(__expf(d0), __expf(NEG_SLOPE * d0),
                                      __expf(d1), __expf(NEG_SLOPE * d1));
            }
        }
    }
}

// ---------------------------------------------------------------------------
// k_bucket: one block per 256-dst bin, 1024 threads (R12: -3us vs 512).
// P1: cnt histogram (1 LDS atomic/edge). Scan -> packed rowPtr
// {beg|cnt<<22}. P2: re-read tmp (L2-hot), gather PS[src] (L2-hot 1.6MB),
// factorized exp-free weight u01 = max-form, counting-sort write of csr
// uint2 {src,u01}. Denominators accumulate in k_agg.
// ---------------------------------------------------------------------------
__global__ __launch_bounds__(1024) void k_bucket(const unsigned int* __restrict__ tmp,
                                                 const int* __restrict__ binCursor,
                                                 const float4* __restrict__ PS,
                                                 const float4* __restrict__ PD,
                                                 uint2* __restrict__ csr,
                                                 unsigned int* __restrict__ rowPtr,
                                                 int N) {
    __shared__ int cnt[256];
    __shared__ int cur[256];
    __shared__ int lds[4];
    __shared__ float4 pdc[256];
    const int t = threadIdx.x;
    const int b = blockIdx.x;
    const int start = b * BCAP;
    const int d0 = b * 256;
    int m = binCursor[b * CURPAD];
    if (m > BCAP) m = BCAP;   // statistically unreachable guard

    if (t < 256) {
        cnt[t] = 0;
        int d = d0 + t;
        pdc[t] = (d < N) ? PD[d] : make_float4(0.f, 0.f, 0.f, 0.f);
    }
    __syncthreads();

    for (int k = t; k < m; k += 1024) {
        atomicAdd(&cnt[tmp[start + k] >> 24], 1);
    }
    __syncthreads();

    const int lane = t & 63, w = t >> 6;
    int v = 0, incl = 0;
    if (t < 256) {                 // waves 0-3 fully active -> shfl safe
        v = cnt[t];
        incl = v;
#pragma unroll
        for (int o = 1; o < 64; o <<= 1) {
            int u = __shfl_up(incl, o);
            if (lane >= o) incl += u;
        }
        if (lane == 63) lds[w] = incl;
    }
    __syncthreads();
    if (t == 0) {
        int run = 0;
        for (int i = 0; i < 4; ++i) { int tv = lds[i]; lds[i] = run; run += tv; }
    }
    __syncthreads();
    if (t < 256) {
        int excl = lds[w] + incl - v;
        cur[t] = excl;
        int d = d0 + t;
        if (d < N) rowPtr[d] = (unsigned)(start + excl) | ((unsigned)v << 22);
    }
    __syncthreads();

    // P2: weight + counting-sort placement
    for (int k = t; k < m; k += 1024) {
        unsigned int e = tmp[start + k];
        int li = e >> 24;
        int s = (int)(e & 0x00FFFFFFu);
        float4 ps = PS[s];
        float4 pd = pdc[li];
        float u0 = fmaxf(ps.x * pd.x, ps.y * pd.y);
        float u1 = fmaxf(ps.z * pd.z, ps.w * pd.w);
        int p = atomicAdd(&cur[li], 1);
        csr[start + p] = make_uint2((unsigned)s, pk_bf16(u0, u1));
    }
}

// ---------------------------------------------------------------------------
// K5: per-dst aggregation + bias + LayerNorm — R12's exact champion loop
// (64.9us @ ~60% VALU / 16 VGPR). R13 lesson: masked-tail clamp+select was
// NOT scalar (compiler demoted to per-lane v_cndmask, VALU 60->86%, +5us);
// the short serial tails (mean deg ~17) are cheaper. Weights arrive packed
// in csr uint2 via uniform (readfirstlane-addressed) loads -> SGPRs; unpack
// is SALU; inner loop = 2 FMA + 2 den-adds per edge. Self weight from
// uniform PS[n]/PD[n] (max-form factorization). 32-bit xp addressing.
// Next csr batch prefetched while gathers + FMAs run.
// ---------------------------------------------------------------------------
__global__ __launch_bounds__(256) void k_agg(const unsigned int* __restrict__ xp,
                                             const float4* __restrict__ PS,
                                             const float4* __restrict__ PD,
                                             const unsigned int* __restrict__ rowPtr,
                                             const uint2* __restrict__ csr,
                                             const float* __restrict__ bias,
                                             const float* __restrict__ gamma,
                                             const float* __restrict__ beta,
                                             float* __restrict__ out, int N) {
    const int w = threadIdx.x >> 6, lane = threadIdx.x & 63;
    const int n = blockIdx.x * 4 + w;
    if (n >= N) return;

    // self weight from factorized exps (f32, unquantized)
    float4 ps = PS[n], pd = PD[n];
    float us0 = fmaxf(ps.x * pd.x, ps.y * pd.y);
    float us1 = fmaxf(ps.z * pd.z, ps.w * pd.w);

    unsigned int vself = xp[((unsigned)n << 6) | lane];
    float S0 = us0 * bf_lo(vself);
    float S1 = us1 * bf_hi(vself);
    float D0 = us0, D1 = us1;

    unsigned int pr = rowPtr[n];
    const int jb = (int)(pr & 0x3FFFFFu);
    const int je = jb + (int)(pr >> 22);
    int j = jb;
    const int nfull = (je - jb) >> 3;

    uint2 cc[8];
    if (nfull > 0) {
        int ju = __builtin_amdgcn_readfirstlane(j);
#pragma unroll
        for (int q = 0; q < 8; ++q) cc[q] = csr[ju + q];
    }
    for (int bI = 0; bI < nfull; ++bI) {
        unsigned int v[8];
#pragma unroll
        for (int q = 0; q < 8; ++q) v[q] = xp[(cc[q].x << 6) | lane];
        // prefetch next csr batch (dummy re-read of jb on the last iteration)
        uint2 cn[8];
        {
            int jn = (bI + 1 < nfull) ? (j + 8) : jb;
            int ju = __builtin_amdgcn_readfirstlane(jn);
#pragma unroll
            for (int q = 0; q < 8; ++q) cn[q] = csr[ju + q];
        }
#pragma unroll
        for (int q = 0; q < 8; ++q) {
            float w0 = bf_lo(cc[q].y), w1 = bf_hi(cc[q].y);
            D0 += w0; D1 += w1;
            S0 = fmaf(w0, bf_lo(v[q]), S0);
            S1 = fmaf(w1, bf_hi(v[q]), S1);
        }
#pragma unroll
        for (int q = 0; q < 8; ++q) cc[q] = cn[q];
        j += 8;
    }
    for (; j + 3 < je; j += 4) {
        int ju = __builtin_amdgcn_readfirstlane(j);
        uint2 c[4];
#pragma unroll
        for (int q = 0; q < 4; ++q) c[q] = csr[ju + q];
        unsigned int v[4];
#pragma unroll
        for (int q = 0; q < 4; ++q) v[q] = xp[(c[q].x << 6) | lane];
#pragma unroll
        for (int q = 0; q < 4; ++q) {
            float w0 = bf_lo(c[q].y), w1 = bf_hi(c[q].y);
            D0 += w0; D1 += w1;
            S0 = fmaf(w0, bf_lo(v[q]), S0);
            S1 = fmaf(w1, bf_hi(v[q]), S1);
        }
    }
    for (; j < je; ++j) {
        uint2 c = csr[__builtin_amdgcn_readfirstlane(j)];
        unsigned int vv = xp[(c.x << 6) | lane];
        float w0 = bf_lo(c.y), w1 = bf_hi(c.y);
        D0 += w0; D1 += w1;
        S0 = fmaf(w0, bf_lo(vv), S0);
        S1 = fmaf(w1, bf_hi(vv), S1);
    }

    float o = (0.5f / (D0 + SM_EPS)) * S0 + (0.5f / (D1 + SM_EPS)) * S1 + bias[lane];

    float mu = o;
#pragma unroll
    for (int d = 32; d > 0; d >>= 1) mu += __shfl_xor(mu, d);
    mu *= (1.0f / 64.0f);
    float dv = o - mu;
    float var = dv * dv;
#pragma unroll
    for (int d = 32; d > 0; d >>= 1) var += __shfl_xor(var, d);
    var *= (1.0f / 64.0f);
    out[(size_t)n * 64 + lane] = dv * rsqrtf(var + LN_EPS) * gamma[lane] + beta[lane];
}

// ---------------------------------------------------------------------------
extern "C" void kernel_launch(void* const* d_in, const int* in_sizes, int n_in,
                              void* d_out, int out_size, void* d_ws, size_t ws_size,
                              hipStream_t stream) {
    const float* X        = (const float*)d_in[0];
    const int*   ei       = (const int*)d_in[1];
    const float* W        = (const float*)d_in[2];
    const float* att_src  = (const float*)d_in[3];
    const float* att_dst  = (const float*)d_in[4];
    const float* bias     = (const float*)d_in[5];
    const float* ln_gamma = (const float*)d_in[6];
    const float* ln_beta  = (const float*)d_in[7];
    float* out = (float*)d_out;

    const int N = in_sizes[0] / 128;
    const int E = in_sizes[1] / 2;
    const int NBUCK = (N + 255) / 256;
    const int SB = (E + SCHUNK - 1) / SCHUNK;
    const int GB = (N + 63) / 64;

    char* ws = (char*)d_ws;
    size_t off = 0;
    auto alloc = [&](size_t bytes) {
        size_t o = off;
        off += (bytes + 255) & ~(size_t)255;
        return o;
    };
    unsigned int* xp     = (unsigned int*)(ws + alloc((size_t)N * 64 * 4));
    float4* PS           = (float4*)(ws + alloc((size_t)N * 16));
    float4* PD           = (float4*)(ws + alloc((size_t)N * 16));
    unsigned int* rowPtr = (unsigned int*)(ws + alloc((size_t)N * 4));
    uint2* csr           = (uint2*)(ws + alloc((size_t)NBIN * BCAP * 8));
    unsigned int* tmp    = (unsigned int*)(ws + alloc((size_t)NBIN * BCAP * 4));
    int* binCursor       = (int*)(ws + alloc(NBIN * CURPAD * 4));

    hipMemsetAsync(binCursor, 0, (size_t)NBIN * CURPAD * 4, stream);
    k_gs<<<SB + GB, 256, 0, stream>>>(X, W, att_src, att_dst, xp, PS, PD,
                                      ei, binCursor, tmp, N, E, SB);
    k_bucket<<<NBUCK, 1024, 0, stream>>>(tmp, binCursor, PS, PD, csr, rowPtr, N);
    k_agg<<<(N + 3) / 4, 256, 0, stream>>>(xp, PS, PD, rowPtr, csr,
                                           bias, ln_gamma, ln_beta, out, N);
}